// Round 6
// baseline (503.203 us; speedup 1.0000x reference)
//
#include <hip/hip_runtime.h>

typedef unsigned short u16;
typedef unsigned int   u32;
typedef _Float16 f16;
typedef _Float16 h2  __attribute__((ext_vector_type(2)));
typedef _Float16 h8  __attribute__((ext_vector_type(8)));
typedef float    fx4 __attribute__((ext_vector_type(4)));

// ---- problem constants ----
// B=4 L=6 X=Y=8 -> 256 sites, W=49 window, D=256, h=8, dh=32
#define SCALE_Q 0.17677669529663687f

__device__ __forceinline__ u16 f2h_bits(float f){
  union{ f16 h; u16 u; } v; v.h = (f16)f; return v.u;
}
__device__ __forceinline__ u32 packh2(float a, float b){
  union{ h2 h; u32 u; } v; v.h = h2{(f16)a, (f16)b}; return v.u;
}
__device__ __forceinline__ h2 as_h2(u32 x){
  union{ u32 u; h2 h; } v; v.u = x; return v.h;
}

// diagnostic fill (fp32): encodes which runtime assumption failed
__global__ void flag_fill(float* out, int n, float v){
  int i = blockIdx.x*256 + threadIdx.x;
  if (i < n) out[i] = v;
}

// ---------------------------------------------------------------------------
// K0: fuse relation matrices into projection weights (fp32 in, f16 out,
// TRANSPOSED for MFMA B-staging): Wft[rel][n][d].
// ---------------------------------------------------------------------------
__global__ __launch_bounds__(512) void fuse_w(
    const float* __restrict__ Wk, const float* __restrict__ Wv,
    const float* __restrict__ Ratt, const float* __restrict__ Rmsg,
    u16* __restrict__ Wft)
{
  const int rel = blockIdx.x;      // 0..3
  const int d   = blockIdx.y;      // 0..255
  const int n   = threadIdx.x;     // 0..511
  const int ml  = rel & 1;
  float acc = 0.f;
  if (n < 256) {
    const int h = n >> 5, p = n & 31;
    const float* wcol = Wk + (size_t)ml*65536 + (size_t)(h*32)*256 + d;
    const float* rrow = Ratt + ((size_t)(rel*8 + h)*32 + p)*32;
    #pragma unroll
    for (int q = 0; q < 32; ++q) acc += wcol[q*256] * rrow[q];
  } else {
    const int n2 = n - 256, h = n2 >> 5, qq = n2 & 31;
    const float* wcol = Wv + (size_t)ml*65536 + (size_t)(h*32)*256 + d;
    const float* rcol = Rmsg + ((size_t)(rel*8 + h)*32)*32 + qq;
    #pragma unroll
    for (int p2 = 0; p2 < 32; ++p2) acc += wcol[p2*256] * rcol[p2*32];
  }
  Wft[((size_t)rel*512 + n)*256 + d] = f2h_bits(acc);
}

__global__ __launch_bounds__(512) void fuse_b(
    const float* __restrict__ bk, const float* __restrict__ bv,
    const float* __restrict__ Ratt, const float* __restrict__ Rmsg,
    float* __restrict__ bff)
{
  const int rel = blockIdx.x, n = threadIdx.x, ml = rel & 1;
  float acc = 0.f;
  if (n < 256) {
    const int h = n >> 5, p = n & 31;
    const float* rrow = Ratt + ((size_t)(rel*8 + h)*32 + p)*32;
    #pragma unroll
    for (int q = 0; q < 32; ++q) acc += bk[ml*256 + h*32 + q] * rrow[q];
  } else {
    const int n2 = n - 256, h = n2 >> 5, qq = n2 & 31;
    const float* rcol = Rmsg + ((size_t)(rel*8 + h)*32)*32 + qq;
    #pragma unroll
    for (int p2 = 0; p2 < 32; ++p2) acc += bv[ml*256 + h*32 + p2] * rcol[p2*32];
  }
  bff[rel*512 + n] = acc;
}

// ---------------------------------------------------------------------------
// K1: fused kw / v_msg projection GEMM — MFMA (16x16x32 f16), FULL-WIDTH.
// BM=64, BN=512 (grid.x==1 -> x fetched from HBM exactly once), BK=32.
// 256 thr = 4 waves. Wave w owns n-columns [w*128, w*128+128): 8 n-tiles x
// 4 m-tiles = 32 MFMA per K-step from 4 af + 8 bf LDS reads (balanced).
// B (Wft, 256 KB/rel) re-stages from L2 per block — cheap.
// Outputs (f16):
//   kw[bloc][xy][h][l][ef][p]   (p-contiguous for QK pair loads)
//   vm[bloc][xy][h][l][p][50]   (ef-contiguous+pad for PV dot2 loads)
// ---------------------------------------------------------------------------
__global__ __launch_bounds__(256) void gemm_kwv(
    const float* __restrict__ x, const int* __restrict__ mode,
    const u16* __restrict__ Wft, const float* __restrict__ bff,
    u16* __restrict__ kw, u16* __restrict__ vm, int b0)
{
  __shared__ u16 As[64*32];    //  4 KB [m][k]
  __shared__ u16 Bs[512*32];   // 32 KB [n][k]
  const int rowT  = blockIdx.x;              // bloc*294 + l*49 + tile
  const int bloc = rowT / 294;
  const int rem  = rowT % 294;
  const int l = rem / 49, tile = rem % 49;
  const int b = b0 + bloc;
  const int rel = mode[b*6]*2 + mode[b*6 + l];
  const float* Abase = x + ((size_t)(b*6 + l)*3136 + (size_t)tile*64)*256;
  const u16*   Bbase = Wft + (size_t)rel*131072;      // [n][d]
  const int tid  = threadIdx.x;
  const int wave = tid >> 6, lane = tid & 63;
  const int quad = lane >> 4, l15 = lane & 15;
  const int srow = tid >> 2, sseg = (tid & 3)*8;      // A staging: 4 thr/row

  fx4 acc[4][8];
  #pragma unroll
  for (int mt = 0; mt < 4; ++mt)
    #pragma unroll
    for (int j = 0; j < 8; ++j) acc[mt][j] = fx4{0,0,0,0};

  for (int k0 = 0; k0 < 256; k0 += 32) {
    // global loads (before barrier so they overlap prior compute)
    float4 a0 = *(const float4*)(Abase + (size_t)srow*256 + k0 + sseg);
    float4 a1 = *(const float4*)(Abase + (size_t)srow*256 + k0 + sseg + 4);
    const u16* r0 = Bbase + (size_t)(2*tid + 0)*256 + k0;
    const u16* r1 = Bbase + (size_t)(2*tid + 1)*256 + k0;
    uint4 bw0[4], bw1[4];
    #pragma unroll
    for (int i = 0; i < 4; ++i){ bw0[i] = ((const uint4*)r0)[i]; bw1[i] = ((const uint4*)r1)[i]; }
    __syncthreads();   // prior iteration's frag reads done
    uint4 ap;
    ap.x = packh2(a0.x, a0.y); ap.y = packh2(a0.z, a0.w);
    ap.z = packh2(a1.x, a1.y); ap.w = packh2(a1.z, a1.w);
    *(uint4*)&As[srow*32 + sseg] = ap;
    #pragma unroll
    for (int i = 0; i < 4; ++i){
      *(uint4*)&Bs[(2*tid + 0)*32 + i*8] = bw0[i];
      *(uint4*)&Bs[(2*tid + 1)*32 + i*8] = bw1[i];
    }
    __syncthreads();
    // fragments + mfma: wave covers 4 m-tiles x 8 n-tiles
    h8 af[4];
    #pragma unroll
    for (int mt = 0; mt < 4; ++mt)
      af[mt] = *(const h8*)&As[(mt*16 + l15)*32 + quad*8];
    #pragma unroll
    for (int j = 0; j < 8; ++j){
      h8 bf = *(const h8*)&Bs[((wave*8 + j)*16 + l15)*32 + quad*8];
      #pragma unroll
      for (int mt = 0; mt < 4; ++mt)
        acc[mt][j] = __builtin_amdgcn_mfma_f32_16x16x32_f16(af[mt], bf, acc[mt][j], 0, 0, 0);
    }
  }

  // epilogue: D row = quad*4+reg (within m-tile), col = l15 (within n-tile)
  #pragma unroll
  for (int j = 0; j < 8; ++j){
    const int n = wave*128 + j*16 + l15;
    const float bias = bff[rel*512 + n];
    #pragma unroll
    for (int mt = 0; mt < 4; ++mt){
      #pragma unroll
      for (int reg = 0; reg < 4; ++reg){
        const int r = tile*64 + mt*16 + quad*4 + reg;   // 0..3135
        const int xy = r / 49, ef = r - xy*49;
        const float val = acc[mt][j][reg] + bias;
        if (n < 256){
          const int hh = n >> 5, p = n & 31;
          kw[((((size_t)(bloc*64 + xy)*8 + hh)*6 + l)*49 + ef)*32 + p] = f2h_bits(val);
        } else {
          const int n2 = n - 256, hh = n2 >> 5, p = n2 & 31;
          vm[((((size_t)(bloc*64 + xy)*8 + hh)*6 + l)*32 + p)*50 + ef] = f2h_bits(val);
        }
      }
    }
  }
}

// ---------------------------------------------------------------------------
// K2: q projection (l=0 only), VALU 4x4, f16 output.
// ---------------------------------------------------------------------------
__global__ __launch_bounds__(256) void gemm_q(
    const float* __restrict__ x, const int* __restrict__ mode,
    const float* __restrict__ Wq, const float* __restrict__ bq,
    u16* __restrict__ qbuf)
{
  __shared__ float As[16][68];
  __shared__ float Bs[16][68];
  const int nbase = blockIdx.x * 64;      // 0..192
  const int rowT  = blockIdx.y;           // 0..195
  const int b = rowT / 49, tile = rowT % 49;
  const int m0 = mode[b*6];
  const float* Abase = x + ((size_t)b*6*3136 + (size_t)tile*64)*256;
  const float* Wbase = Wq + (size_t)m0*65536;
  const int tid = threadIdx.x;
  const int tx = tid & 15, ty = tid >> 4;
  const int arow = tid >> 2, acol = (tid & 3)*4;
  const int bn = tid >> 2,  bk4 = (tid & 3)*4;
  float acc[4][4] = {};
  for (int k0 = 0; k0 < 256; k0 += 16) {
    float4 ar = *(const float4*)(Abase + (size_t)arow*256 + k0 + acol);
    float4 br = *(const float4*)(Wbase + (size_t)(nbase + bn)*256 + k0 + bk4);
    __syncthreads();
    As[acol+0][arow]=ar.x; As[acol+1][arow]=ar.y; As[acol+2][arow]=ar.z; As[acol+3][arow]=ar.w;
    Bs[bk4+0][bn]=br.x; Bs[bk4+1][bn]=br.y; Bs[bk4+2][bn]=br.z; Bs[bk4+3][bn]=br.w;
    __syncthreads();
    #pragma unroll
    for (int kk = 0; kk < 16; ++kk){
      float4 a4 = *(const float4*)&As[kk][ty*4];
      float4 b4 = *(const float4*)&Bs[kk][tx*4];
      float ar_[4] = {a4.x,a4.y,a4.z,a4.w};
      float br_[4] = {b4.x,b4.y,b4.z,b4.w};
      #pragma unroll
      for (int i = 0; i < 4; ++i)
        #pragma unroll
        for (int j = 0; j < 4; ++j) acc[i][j] += ar_[i]*br_[j];
    }
  }
  const int colBase = nbase + tx*4;
  const int h = colBase >> 5, p = colBase & 31;
  float bias[4];
  #pragma unroll
  for (int j = 0; j < 4; ++j) bias[j] = bq[m0*256 + colBase + j];
  #pragma unroll
  for (int i = 0; i < 4; ++i){
    int r = tile*64 + ty*4 + i;
    int xy = r / 49, ef = r - xy*49;
    size_t dst = (((size_t)(b*64 + xy)*8 + h)*49 + ef)*32 + p;
    ushort4 pk;
    pk.x = f2h_bits((acc[i][0]+bias[0])*SCALE_Q);
    pk.y = f2h_bits((acc[i][1]+bias[1])*SCALE_Q);
    pk.z = f2h_bits((acc[i][2]+bias[2])*SCALE_Q);
    pk.w = f2h_bits((acc[i][3]+bias[3])*SCALE_Q);
    *(ushort4*)(qbuf + dst) = pk;
  }
}

// ---------------------------------------------------------------------------
// K3: attention — ONE WAVE per (bloc,xy,h); lane = query row qi (49 active).
// Scores S[49], online-softmax state, O[32] all in REGISTERS.
// K_z / V^T_z staged in LDS, read via broadcast b128 (conflict-free).
// QK^T and PV via v_dot2_f32_f16. LDS = 10192+3136+3584+676 = 17.6 KB.
// ---------------------------------------------------------------------------
__global__ __launch_bounds__(64) void attn_kernel(
    const u16* __restrict__ qbuf, const u16* __restrict__ kw,
    const u16* __restrict__ vm,   const float* __restrict__ post,
    u16* __restrict__ aout, int b0)
{
  __shared__ float biasT[49*52];   // [ke][qi] — lane-linear reads
  __shared__ u32 Ks[784];          // K_z  flat [ef*16 + pp]
  __shared__ u32 VTs[32*28];       // V^T_z [p][28] (25 used, 3 pad)
  __shared__ float poss[169];

  const int bloc  = blockIdx.x >> 9;
  const int local = blockIdx.x & 511;      // xy*8+h
  const int h = local & 7, xy = local >> 3;
  const int bxy = (b0 + bloc)*64 + xy;
  const int tid = threadIdx.x;             // 0..63
  const int qi = min(tid, 48);             // lane's query row (clamped)

  for (int i = tid; i < 169; i += 64) poss[i] = post[i*8 + h];
  __syncthreads();

  if (tid < 49){
    const int qa = qi/7, qb = qi - qa*7;
    for (int ka = 0; ka < 7; ++ka)
      for (int kb = 0; kb < 7; ++kb)
        biasT[(ka*7+kb)*52 + qi] = poss[(qa - ka + 6)*13 + (qb - kb + 6)];
  }

  // Q row into registers (16 u32 = 32 f16)
  u32 Qw[16];
  { const uint4* qsrc = (const uint4*)(qbuf + (size_t)(bxy*8 + h)*1568 + (size_t)qi*32);
    uint4 t0 = qsrc[0], t1 = qsrc[1], t2 = qsrc[2], t3 = qsrc[3];
    Qw[0]=t0.x; Qw[1]=t0.y; Qw[2]=t0.z; Qw[3]=t0.w;
    Qw[4]=t1.x; Qw[5]=t1.y; Qw[6]=t1.z; Qw[7]=t1.w;
    Qw[8]=t2.x; Qw[9]=t2.y; Qw[10]=t2.z; Qw[11]=t2.w;
    Qw[12]=t3.x; Qw[13]=t3.y; Qw[14]=t3.z; Qw[15]=t3.w; }

  const size_t kvbase = ((size_t)(bloc*64 + xy)*8 + h)*6;
  float mprev = -1e30f, lsum = 0.f;
  float O[32];
  #pragma unroll
  for (int p = 0; p < 32; ++p) O[p] = 0.f;

  for (int z = 0; z < 6; ++z){
    __syncthreads();   // prior phase's LDS reads complete (also covers biasT build)
    { const u32* ksrc = (const u32*)(kw) + (kvbase + z)*49*16;
      for (int i = tid; i < 784; i += 64) Ks[i] = ksrc[i];
      const u32* vsrc = (const u32*)(vm) + (kvbase + z)*32*25;
      for (int i = tid; i < 800; i += 64){
        int p = i / 25, rm = i - p*25;
        VTs[p*28 + rm] = vsrc[i];
      } }
    __syncthreads();

    // ---- S[ke] = q . k_z + bias ----
    float S[49];
    #pragma unroll
    for (int ke = 0; ke < 49; ++ke){
      float s = biasT[ke*52 + qi];
      #pragma unroll
      for (int q4 = 0; q4 < 4; ++q4){
        uint4 k4 = *(const uint4*)&Ks[ke*16 + q4*4];
        s = __builtin_amdgcn_fdot2(as_h2(Qw[q4*4+0]), as_h2(k4.x), s, false);
        s = __builtin_amdgcn_fdot2(as_h2(Qw[q4*4+1]), as_h2(k4.y), s, false);
        s = __builtin_amdgcn_fdot2(as_h2(Qw[q4*4+2]), as_h2(k4.z), s, false);
        s = __builtin_amdgcn_fdot2(as_h2(Qw[q4*4+3]), as_h2(k4.w), s, false);
      }
      S[ke] = s;
    }

    // ---- online softmax (lane-local) ----
    float mx = mprev;
    #pragma unroll
    for (int ke = 0; ke < 49; ++ke) mx = fmaxf(mx, S[ke]);
    const float alpha = __expf(mprev - mx);
    float sum = 0.f;
    #pragma unroll
    for (int ke = 0; ke < 49; ++ke){ float e = __expf(S[ke]-mx); S[ke] = e; sum += e; }
    lsum = lsum*alpha + sum;
    mprev = mx;
    #pragma unroll
    for (int p = 0; p < 32; ++p) O[p] *= alpha;

    // ---- pack P to f16 pairs ----
    u32 Pp[25];
    #pragma unroll
    for (int kp = 0; kp < 24; ++kp) Pp[kp] = packh2(S[2*kp], S[2*kp+1]);
    Pp[24] = packh2(S[48], 0.f);

    // ---- O += P . V_z ----
    #pragma unroll
    for (int p = 0; p < 32; ++p){
      float o = O[p];
      #pragma unroll
      for (int c = 0; c < 6; ++c){
        uint4 v4 = *(const uint4*)&VTs[p*28 + c*4];
        o = __builtin_amdgcn_fdot2(as_h2(Pp[c*4+0]), as_h2(v4.x), o, false);
        o = __builtin_amdgcn_fdot2(as_h2(Pp[c*4+1]), as_h2(v4.y), o, false);
        o = __builtin_amdgcn_fdot2(as_h2(Pp[c*4+2]), as_h2(v4.z), o, false);
        o = __builtin_amdgcn_fdot2(as_h2(Pp[c*4+3]), as_h2(v4.w), o, false);
      }
      o = __builtin_amdgcn_fdot2(as_h2(Pp[24]), as_h2(VTs[p*28 + 24]), o, false);
      O[p] = o;
    }
  }

  // ---- normalize + store (f16) ----
  if (tid < 49){
    const float inv = 1.f / lsum;
    u32* outw = (u32*)(aout + (size_t)bxy*12544 + h*32);
    #pragma unroll
    for (int pp = 0; pp < 16; ++pp)
      outw[(size_t)qi*128 + pp] = packh2(O[2*pp]*inv, O[2*pp+1]*inv);
  }
}

// ---------------------------------------------------------------------------
// K4: final projection. A = attn out (f16), B = Wa[m0] fp32 [e][d], bias ba.
// ---------------------------------------------------------------------------
__global__ __launch_bounds__(256) void gemm_out(
    const u16* __restrict__ aout, const int* __restrict__ mode,
    const float* __restrict__ Wa, const float* __restrict__ ba,
    float* __restrict__ outp)
{
  __shared__ float As[16][68];
  __shared__ float Bs[16][68];
  const int nbase = blockIdx.x * 64;
  const int rowT  = blockIdx.y;           // 0..195
  const int b = rowT / 49, tile = rowT % 49;
  const int m0 = mode[b*6];
  const u16* Abase = aout + ((size_t)b*3136 + (size_t)tile*64)*256;
  const float* Wbase = Wa + (size_t)m0*65536;
  const int tid = threadIdx.x;
  const int tx = tid & 15, ty = tid >> 4;
  const int arow = tid >> 2, acol = (tid & 3)*4;
  const int bn = tid >> 2,  bk4 = (tid & 3)*4;
  float acc[4][4] = {};
  for (int k0 = 0; k0 < 256; k0 += 16) {
    uint2  ar = *(const uint2*)(Abase + (size_t)arow*256 + k0 + acol);
    float4 br = *(const float4*)(Wbase + (size_t)(nbase + bn)*256 + k0 + bk4);
    __syncthreads();
    { h2 lo = as_h2(ar.x), hi = as_h2(ar.y);
      As[acol+0][arow]=(float)lo.x; As[acol+1][arow]=(float)lo.y;
      As[acol+2][arow]=(float)hi.x; As[acol+3][arow]=(float)hi.y; }
    Bs[bk4+0][bn]=br.x; Bs[bk4+1][bn]=br.y; Bs[bk4+2][bn]=br.z; Bs[bk4+3][bn]=br.w;
    __syncthreads();
    #pragma unroll
    for (int kk = 0; kk < 16; ++kk){
      float4 a4 = *(const float4*)&As[kk][ty*4];
      float4 b4 = *(const float4*)&Bs[kk][tx*4];
      float ar_[4] = {a4.x,a4.y,a4.z,a4.w};
      float br_[4] = {b4.x,b4.y,b4.z,b4.w};
      #pragma unroll
      for (int i = 0; i < 4; ++i)
        #pragma unroll
        for (int j = 0; j < 4; ++j) acc[i][j] += ar_[i]*br_[j];
    }
  }
  const int colBase = nbase + tx*4;
  float bias[4];
  #pragma unroll
  for (int j = 0; j < 4; ++j) bias[j] = ba[m0*256 + colBase + j];
  #pragma unroll
  for (int i = 0; i < 4; ++i){
    int rowg = b*3136 + tile*64 + ty*4 + i;
    float4 o;
    o.x = acc[i][0] + bias[0];
    o.y = acc[i][1] + bias[1];
    o.z = acc[i][2] + bias[2];
    o.w = acc[i][3] + bias[3];
    *(float4*)(outp + (size_t)rowg*256 + colBase) = o;
  }
}

// ---------------------------------------------------------------------------
extern "C" void kernel_launch(void* const* d_in, const int* in_sizes, int n_in,
                              void* d_out, int out_size, void* d_ws, size_t ws_size,
                              hipStream_t stream)
{
  float* outp = (float*)d_out;
  const int FLAG_GRID = (out_size + 255)/256;

  if (n_in != 13) { flag_fill<<<FLAG_GRID,256,0,stream>>>(outp, out_size, 2000.f); return; }
  if (in_sizes[0] != 4*6*64*49*256) { flag_fill<<<FLAG_GRID,256,0,stream>>>(outp, out_size, 3000.f); return; }
  if (in_sizes[1] != 24) { flag_fill<<<FLAG_GRID,256,0,stream>>>(outp, out_size, 4000.f); return; }

  const size_t SZ_WFT  = (size_t)4*512*256*2;               //  1 MB (f16)
  const size_t SZ_BFF  = (size_t)4*512*sizeof(float);       //  8 KB
  const size_t SZ_Q    = (size_t)12544*256*2;               //  6.4 MB (f16)
  const size_t SZ_AOUT = (size_t)12544*256*2;               //  6.4 MB (f16)
  const size_t SZ_KW1  = (size_t)64*8*6*49*32*2;            //  9.63 MB / batch
  const size_t SZ_VM1  = (size_t)64*8*6*32*50*2;            //  9.83 MB / batch
  const size_t FIXED   = SZ_WFT + SZ_BFF + SZ_Q + SZ_AOUT;
  if (ws_size < FIXED + SZ_KW1 + SZ_VM1) { flag_fill<<<FLAG_GRID,256,0,stream>>>(outp, out_size, 1000.f); return; }

  int nb = 1;
  if (ws_size >= FIXED + 4*(SZ_KW1 + SZ_VM1)) nb = 4;
  else if (ws_size >= FIXED + 2*(SZ_KW1 + SZ_VM1)) nb = 2;

  const float* x    = (const float*)d_in[0];
  const int*   mode = (const int*)d_in[1];
  const float* Wq   = (const float*)d_in[2];
  const float* bq   = (const float*)d_in[3];
  const float* Wk   = (const float*)d_in[4];
  const float* bk   = (const float*)d_in[5];
  const float* Wv   = (const float*)d_in[6];
  const float* bv   = (const float*)d_in[7];
  const float* Wa   = (const float*)d_in[8];
  const float* ba   = (const float*)d_in[9];
  const float* Ratt = (const float*)d_in[10];
  const float* Rmsg = (const float*)d_in[11];
  const float* post = (const float*)d_in[12];

  char* w = (char*)d_ws;
  u16* Wft   = (u16*)w;   w += SZ_WFT;
  float* bff = (float*)w; w += SZ_BFF;
  u16* qbuf  = (u16*)w;   w += SZ_Q;
  u16* aout  = (u16*)w;   w += SZ_AOUT;
  u16* kwbuf = (u16*)w;   w += (size_t)nb*SZ_KW1;
  u16* vmbuf = (u16*)w;   w += (size_t)nb*SZ_VM1;

  fuse_w<<<dim3(4,256), 512, 0, stream>>>(Wk, Wv, Ratt, Rmsg, Wft);
  fuse_b<<<4, 512, 0, stream>>>(bk, bv, Ratt, Rmsg, bff);
  gemm_q<<<dim3(4,196), 256, 0, stream>>>(x, mode, Wq, bq, qbuf);
  for (int b0 = 0; b0 < 4; b0 += nb) {
    gemm_kwv<<<nb*294, 256, 0, stream>>>(x, mode, Wft, bff, kwbuf, vmbuf, b0);
    attn_kernel<<<nb*512, 64, 0, stream>>>(qbuf, kwbuf, vmbuf, post, aout, b0);
  }
  gemm_out<<<dim3(4,196), 256, 0, stream>>>(aout, mode, Wa, ba, outp);
}

// Round 7
// 417.830 us; speedup vs baseline: 1.2043x; 1.2043x over previous
//
#include <hip/hip_runtime.h>

typedef unsigned short u16;
typedef unsigned int   u32;
typedef _Float16 f16;
typedef _Float16 h2  __attribute__((ext_vector_type(2)));
typedef _Float16 h8  __attribute__((ext_vector_type(8)));
typedef float    fx4 __attribute__((ext_vector_type(4)));

// ---- problem constants ----
// B=4 L=6 X=Y=8 -> 256 sites, W=49 window, D=256, h=8, dh=32
#define SCALE_Q 0.17677669529663687f

__device__ __forceinline__ u16 f2h_bits(float f){
  union{ f16 h; u16 u; } v; v.h = (f16)f; return v.u;
}
__device__ __forceinline__ u32 packh2(float a, float b){
  union{ h2 h; u32 u; } v; v.h = h2{(f16)a, (f16)b}; return v.u;
}
__device__ __forceinline__ h2 as_h2(u32 x){
  union{ u32 u; h2 h; } v; v.u = x; return v.h;
}

// diagnostic fill (fp32): encodes which runtime assumption failed
__global__ void flag_fill(float* out, int n, float v){
  int i = blockIdx.x*256 + threadIdx.x;
  if (i < n) out[i] = v;
}

// ---------------------------------------------------------------------------
// K0: fuse relation matrices into projection weights (fp32 in, f16 out,
// TRANSPOSED for MFMA B-access): Wft[rel][n][d].
// ---------------------------------------------------------------------------
__global__ __launch_bounds__(512) void fuse_w(
    const float* __restrict__ Wk, const float* __restrict__ Wv,
    const float* __restrict__ Ratt, const float* __restrict__ Rmsg,
    u16* __restrict__ Wft)
{
  const int rel = blockIdx.x;      // 0..3
  const int d   = blockIdx.y;      // 0..255
  const int n   = threadIdx.x;     // 0..511
  const int ml  = rel & 1;
  float acc = 0.f;
  if (n < 256) {
    const int h = n >> 5, p = n & 31;
    const float* wcol = Wk + (size_t)ml*65536 + (size_t)(h*32)*256 + d;
    const float* rrow = Ratt + ((size_t)(rel*8 + h)*32 + p)*32;
    #pragma unroll
    for (int q = 0; q < 32; ++q) acc += wcol[q*256] * rrow[q];
  } else {
    const int n2 = n - 256, h = n2 >> 5, qq = n2 & 31;
    const float* wcol = Wv + (size_t)ml*65536 + (size_t)(h*32)*256 + d;
    const float* rcol = Rmsg + ((size_t)(rel*8 + h)*32)*32 + qq;
    #pragma unroll
    for (int p2 = 0; p2 < 32; ++p2) acc += wcol[p2*256] * rcol[p2*32];
  }
  Wft[((size_t)rel*512 + n)*256 + d] = f2h_bits(acc);
}

__global__ __launch_bounds__(512) void fuse_b(
    const float* __restrict__ bk, const float* __restrict__ bv,
    const float* __restrict__ Ratt, const float* __restrict__ Rmsg,
    float* __restrict__ bff)
{
  const int rel = blockIdx.x, n = threadIdx.x, ml = rel & 1;
  float acc = 0.f;
  if (n < 256) {
    const int h = n >> 5, p = n & 31;
    const float* rrow = Ratt + ((size_t)(rel*8 + h)*32 + p)*32;
    #pragma unroll
    for (int q = 0; q < 32; ++q) acc += bk[ml*256 + h*32 + q] * rrow[q];
  } else {
    const int n2 = n - 256, h = n2 >> 5, qq = n2 & 31;
    const float* rcol = Rmsg + ((size_t)(rel*8 + h)*32)*32 + qq;
    #pragma unroll
    for (int p2 = 0; p2 < 32; ++p2) acc += bv[ml*256 + h*32 + p2] * rcol[p2*32];
  }
  bff[rel*512 + n] = acc;
}

// ---------------------------------------------------------------------------
// K1 v3: fused kw / v_msg projection GEMM — MFMA (16x16x32 f16).
// BM=32, BN=512, grid = nb*588 (x fetched from HBM exactly once).
// A (32x256 fp32) staged to LDS f16 ONCE per block (padded stride 264),
// then the k-loop is barrier-free: 2 ds_read_b128 + 8 global b128 (B direct
// from L2-resident Wft — no LDS, no bank conflicts) + 16 MFMA per wave/step.
// acc[2][8] = 64 VGPRs -> ~3-4 waves/SIMD occupancy.
// Outputs (f16):
//   kw[bloc][xy][h][l][ef][p]   (p-contiguous for QK pair loads)
//   vm[bloc][xy][h][l][p][50]   (ef-contiguous+pad for PV dot2 loads)
// ---------------------------------------------------------------------------
#define ASTRIDE 264   // u16 elements per A-row in LDS (16B-aligned, bank-friendly)

__global__ __launch_bounds__(256) void gemm_kwv(
    const float* __restrict__ x, const int* __restrict__ mode,
    const u16* __restrict__ Wft, const float* __restrict__ bff,
    u16* __restrict__ kw, u16* __restrict__ vm, int b0)
{
  __shared__ u16 As[32*ASTRIDE];   // 16.9 KB, [m][k] padded
  const int rowT  = blockIdx.x;              // bloc*588 + l*98 + tile
  const int bloc = rowT / 588;
  const int rem  = rowT % 588;
  const int l = rem / 98, tile = rem % 98;
  const int b = b0 + bloc;
  const int rel = mode[b*6]*2 + mode[b*6 + l];
  const float* Abase = x + ((size_t)(b*6 + l)*3136 + (size_t)tile*32)*256;
  const u16*   Bbase = Wft + (size_t)rel*131072;      // [n][d]
  const int tid  = threadIdx.x;
  const int wave = tid >> 6, lane = tid & 63;
  const int quad = lane >> 4, l15 = lane & 15;

  // ---- stage A once: thread t loads row t>>3, cols (t&7)*32..+31 ----
  {
    const int r = tid >> 3, cseg = (tid & 7)*32;
    const float* src = Abase + (size_t)r*256 + cseg;
    u16* dst = &As[r*ASTRIDE + cseg];
    #pragma unroll
    for (int i = 0; i < 4; ++i){
      float4 f0 = *(const float4*)(src + i*8);
      float4 f1 = *(const float4*)(src + i*8 + 4);
      uint4 pk;
      pk.x = packh2(f0.x, f0.y); pk.y = packh2(f0.z, f0.w);
      pk.z = packh2(f1.x, f1.y); pk.w = packh2(f1.z, f1.w);
      *(uint4*)(dst + i*8) = pk;
    }
  }
  __syncthreads();

  fx4 acc[2][8];
  #pragma unroll
  for (int mt = 0; mt < 2; ++mt)
    #pragma unroll
    for (int j = 0; j < 8; ++j) acc[mt][j] = fx4{0,0,0,0};

  // wave owns n-columns [wave*128, wave*128+128): 8 n-tiles x 2 m-tiles
  for (int k0 = 0; k0 < 256; k0 += 32) {
    h8 af[2];
    #pragma unroll
    for (int mt = 0; mt < 2; ++mt)
      af[mt] = *(const h8*)&As[(mt*16 + l15)*ASTRIDE + k0 + quad*8];
    #pragma unroll
    for (int j = 0; j < 8; ++j){
      const int n = wave*128 + j*16 + l15;
      h8 bf = *(const h8*)(Bbase + (size_t)n*256 + k0 + quad*8);
      #pragma unroll
      for (int mt = 0; mt < 2; ++mt)
        acc[mt][j] = __builtin_amdgcn_mfma_f32_16x16x32_f16(af[mt], bf, acc[mt][j], 0, 0, 0);
    }
  }

  // epilogue: D row = quad*4+reg (within m-tile), col = l15 (within n-tile)
  #pragma unroll
  for (int j = 0; j < 8; ++j){
    const int n = wave*128 + j*16 + l15;
    const float bias = bff[rel*512 + n];
    #pragma unroll
    for (int mt = 0; mt < 2; ++mt){
      #pragma unroll
      for (int reg = 0; reg < 4; ++reg){
        const int r = tile*32 + mt*16 + quad*4 + reg;   // 0..3135
        const int xy = r / 49, ef = r - xy*49;
        const float val = acc[mt][j][reg] + bias;
        if (n < 256){
          const int hh = n >> 5, p = n & 31;
          kw[((((size_t)(bloc*64 + xy)*8 + hh)*6 + l)*49 + ef)*32 + p] = f2h_bits(val);
        } else {
          const int n2 = n - 256, hh = n2 >> 5, p = n2 & 31;
          vm[((((size_t)(bloc*64 + xy)*8 + hh)*6 + l)*32 + p)*50 + ef] = f2h_bits(val);
        }
      }
    }
  }
}

// ---------------------------------------------------------------------------
// K2: q projection (l=0 only), VALU 4x4, f16 output.
// ---------------------------------------------------------------------------
__global__ __launch_bounds__(256) void gemm_q(
    const float* __restrict__ x, const int* __restrict__ mode,
    const float* __restrict__ Wq, const float* __restrict__ bq,
    u16* __restrict__ qbuf)
{
  __shared__ float As[16][68];
  __shared__ float Bs[16][68];
  const int nbase = blockIdx.x * 64;      // 0..192
  const int rowT  = blockIdx.y;           // 0..195
  const int b = rowT / 49, tile = rowT % 49;
  const int m0 = mode[b*6];
  const float* Abase = x + ((size_t)b*6*3136 + (size_t)tile*64)*256;
  const float* Wbase = Wq + (size_t)m0*65536;
  const int tid = threadIdx.x;
  const int tx = tid & 15, ty = tid >> 4;
  const int arow = tid >> 2, acol = (tid & 3)*4;
  const int bn = tid >> 2,  bk4 = (tid & 3)*4;
  float acc[4][4] = {};
  for (int k0 = 0; k0 < 256; k0 += 16) {
    float4 ar = *(const float4*)(Abase + (size_t)arow*256 + k0 + acol);
    float4 br = *(const float4*)(Wbase + (size_t)(nbase + bn)*256 + k0 + bk4);
    __syncthreads();
    As[acol+0][arow]=ar.x; As[acol+1][arow]=ar.y; As[acol+2][arow]=ar.z; As[acol+3][arow]=ar.w;
    Bs[bk4+0][bn]=br.x; Bs[bk4+1][bn]=br.y; Bs[bk4+2][bn]=br.z; Bs[bk4+3][bn]=br.w;
    __syncthreads();
    #pragma unroll
    for (int kk = 0; kk < 16; ++kk){
      float4 a4 = *(const float4*)&As[kk][ty*4];
      float4 b4 = *(const float4*)&Bs[kk][tx*4];
      float ar_[4] = {a4.x,a4.y,a4.z,a4.w};
      float br_[4] = {b4.x,b4.y,b4.z,b4.w};
      #pragma unroll
      for (int i = 0; i < 4; ++i)
        #pragma unroll
        for (int j = 0; j < 4; ++j) acc[i][j] += ar_[i]*br_[j];
    }
  }
  const int colBase = nbase + tx*4;
  const int h = colBase >> 5, p = colBase & 31;
  float bias[4];
  #pragma unroll
  for (int j = 0; j < 4; ++j) bias[j] = bq[m0*256 + colBase + j];
  #pragma unroll
  for (int i = 0; i < 4; ++i){
    int r = tile*64 + ty*4 + i;
    int xy = r / 49, ef = r - xy*49;
    size_t dst = (((size_t)(b*64 + xy)*8 + h)*49 + ef)*32 + p;
    ushort4 pk;
    pk.x = f2h_bits((acc[i][0]+bias[0])*SCALE_Q);
    pk.y = f2h_bits((acc[i][1]+bias[1])*SCALE_Q);
    pk.z = f2h_bits((acc[i][2]+bias[2])*SCALE_Q);
    pk.w = f2h_bits((acc[i][3]+bias[3])*SCALE_Q);
    *(ushort4*)(qbuf + dst) = pk;
  }
}

// ---------------------------------------------------------------------------
// K3: attention — ONE WAVE per (bloc,xy,h); lane = query row qi (49 active).
// Scores S[49], online-softmax state, O[32] all in REGISTERS.
// K_z / V^T_z staged in LDS, read via broadcast b128 (conflict-free).
// QK^T and PV via v_dot2_f32_f16. LDS = 10192+3136+3584+676 = 17.6 KB.
// ---------------------------------------------------------------------------
__global__ __launch_bounds__(64) void attn_kernel(
    const u16* __restrict__ qbuf, const u16* __restrict__ kw,
    const u16* __restrict__ vm,   const float* __restrict__ post,
    u16* __restrict__ aout, int b0)
{
  __shared__ float biasT[49*52];   // [ke][qi] — lane-linear reads
  __shared__ u32 Ks[784];          // K_z  flat [ef*16 + pp]
  __shared__ u32 VTs[32*28];       // V^T_z [p][28] (25 used, 3 pad)
  __shared__ float poss[169];

  const int bloc  = blockIdx.x >> 9;
  const int local = blockIdx.x & 511;      // xy*8+h
  const int h = local & 7, xy = local >> 3;
  const int bxy = (b0 + bloc)*64 + xy;
  const int tid = threadIdx.x;             // 0..63
  const int qi = min(tid, 48);             // lane's query row (clamped)

  for (int i = tid; i < 169; i += 64) poss[i] = post[i*8 + h];
  __syncthreads();

  if (tid < 49){
    const int qa = qi/7, qb = qi - qa*7;
    for (int ka = 0; ka < 7; ++ka)
      for (int kb = 0; kb < 7; ++kb)
        biasT[(ka*7+kb)*52 + qi] = poss[(qa - ka + 6)*13 + (qb - kb + 6)];
  }

  // Q row into registers (16 u32 = 32 f16)
  u32 Qw[16];
  { const uint4* qsrc = (const uint4*)(qbuf + (size_t)(bxy*8 + h)*1568 + (size_t)qi*32);
    uint4 t0 = qsrc[0], t1 = qsrc[1], t2 = qsrc[2], t3 = qsrc[3];
    Qw[0]=t0.x; Qw[1]=t0.y; Qw[2]=t0.z; Qw[3]=t0.w;
    Qw[4]=t1.x; Qw[5]=t1.y; Qw[6]=t1.z; Qw[7]=t1.w;
    Qw[8]=t2.x; Qw[9]=t2.y; Qw[10]=t2.z; Qw[11]=t2.w;
    Qw[12]=t3.x; Qw[13]=t3.y; Qw[14]=t3.z; Qw[15]=t3.w; }

  const size_t kvbase = ((size_t)(bloc*64 + xy)*8 + h)*6;
  float mprev = -1e30f, lsum = 0.f;
  float O[32];
  #pragma unroll
  for (int p = 0; p < 32; ++p) O[p] = 0.f;

  for (int z = 0; z < 6; ++z){
    __syncthreads();   // prior phase's LDS reads complete (also covers biasT build)
    { const u32* ksrc = (const u32*)(kw) + (kvbase + z)*49*16;
      for (int i = tid; i < 784; i += 64) Ks[i] = ksrc[i];
      const u32* vsrc = (const u32*)(vm) + (kvbase + z)*32*25;
      for (int i = tid; i < 800; i += 64){
        int p = i / 25, rm = i - p*25;
        VTs[p*28 + rm] = vsrc[i];
      } }
    __syncthreads();

    // ---- S[ke] = q . k_z + bias ----
    float S[49];
    #pragma unroll
    for (int ke = 0; ke < 49; ++ke){
      float s = biasT[ke*52 + qi];
      #pragma unroll
      for (int q4 = 0; q4 < 4; ++q4){
        uint4 k4 = *(const uint4*)&Ks[ke*16 + q4*4];
        s = __builtin_amdgcn_fdot2(as_h2(Qw[q4*4+0]), as_h2(k4.x), s, false);
        s = __builtin_amdgcn_fdot2(as_h2(Qw[q4*4+1]), as_h2(k4.y), s, false);
        s = __builtin_amdgcn_fdot2(as_h2(Qw[q4*4+2]), as_h2(k4.z), s, false);
        s = __builtin_amdgcn_fdot2(as_h2(Qw[q4*4+3]), as_h2(k4.w), s, false);
      }
      S[ke] = s;
    }

    // ---- online softmax (lane-local) ----
    float mx = mprev;
    #pragma unroll
    for (int ke = 0; ke < 49; ++ke) mx = fmaxf(mx, S[ke]);
    const float alpha = __expf(mprev - mx);
    float sum = 0.f;
    #pragma unroll
    for (int ke = 0; ke < 49; ++ke){ float e = __expf(S[ke]-mx); S[ke] = e; sum += e; }
    lsum = lsum*alpha + sum;
    mprev = mx;
    #pragma unroll
    for (int p = 0; p < 32; ++p) O[p] *= alpha;

    // ---- pack P to f16 pairs ----
    u32 Pp[25];
    #pragma unroll
    for (int kp = 0; kp < 24; ++kp) Pp[kp] = packh2(S[2*kp], S[2*kp+1]);
    Pp[24] = packh2(S[48], 0.f);

    // ---- O += P . V_z ----
    #pragma unroll
    for (int p = 0; p < 32; ++p){
      float o = O[p];
      #pragma unroll
      for (int c = 0; c < 6; ++c){
        uint4 v4 = *(const uint4*)&VTs[p*28 + c*4];
        o = __builtin_amdgcn_fdot2(as_h2(Pp[c*4+0]), as_h2(v4.x), o, false);
        o = __builtin_amdgcn_fdot2(as_h2(Pp[c*4+1]), as_h2(v4.y), o, false);
        o = __builtin_amdgcn_fdot2(as_h2(Pp[c*4+2]), as_h2(v4.z), o, false);
        o = __builtin_amdgcn_fdot2(as_h2(Pp[c*4+3]), as_h2(v4.w), o, false);
      }
      o = __builtin_amdgcn_fdot2(as_h2(Pp[24]), as_h2(VTs[p*28 + 24]), o, false);
      O[p] = o;
    }
  }

  // ---- normalize + store (f16) ----
  if (tid < 49){
    const float inv = 1.f / lsum;
    u32* outw = (u32*)(aout + (size_t)bxy*12544 + h*32);
    #pragma unroll
    for (int pp = 0; pp < 16; ++pp)
      outw[(size_t)qi*128 + pp] = packh2(O[2*pp]*inv, O[2*pp+1]*inv);
  }
}

// ---------------------------------------------------------------------------
// K4: final projection. A = attn out (f16), B = Wa[m0] fp32 [e][d], bias ba.
// ---------------------------------------------------------------------------
__global__ __launch_bounds__(256) void gemm_out(
    const u16* __restrict__ aout, const int* __restrict__ mode,
    const float* __restrict__ Wa, const float* __restrict__ ba,
    float* __restrict__ outp)
{
  __shared__ float As[16][68];
  __shared__ float Bs[16][68];
  const int nbase = blockIdx.x * 64;
  const int rowT  = blockIdx.y;           // 0..195
  const int b = rowT / 49, tile = rowT % 49;
  const int m0 = mode[b*6];
  const u16* Abase = aout + ((size_t)b*3136 + (size_t)tile*64)*256;
  const float* Wbase = Wa + (size_t)m0*65536;
  const int tid = threadIdx.x;
  const int tx = tid & 15, ty = tid >> 4;
  const int arow = tid >> 2, acol = (tid & 3)*4;
  const int bn = tid >> 2,  bk4 = (tid & 3)*4;
  float acc[4][4] = {};
  for (int k0 = 0; k0 < 256; k0 += 16) {
    uint2  ar = *(const uint2*)(Abase + (size_t)arow*256 + k0 + acol);
    float4 br = *(const float4*)(Wbase + (size_t)(nbase + bn)*256 + k0 + bk4);
    __syncthreads();
    { h2 lo = as_h2(ar.x), hi = as_h2(ar.y);
      As[acol+0][arow]=(float)lo.x; As[acol+1][arow]=(float)lo.y;
      As[acol+2][arow]=(float)hi.x; As[acol+3][arow]=(float)hi.y; }
    Bs[bk4+0][bn]=br.x; Bs[bk4+1][bn]=br.y; Bs[bk4+2][bn]=br.z; Bs[bk4+3][bn]=br.w;
    __syncthreads();
    #pragma unroll
    for (int kk = 0; kk < 16; ++kk){
      float4 a4 = *(const float4*)&As[kk][ty*4];
      float4 b4 = *(const float4*)&Bs[kk][tx*4];
      float ar_[4] = {a4.x,a4.y,a4.z,a4.w};
      float br_[4] = {b4.x,b4.y,b4.z,b4.w};
      #pragma unroll
      for (int i = 0; i < 4; ++i)
        #pragma unroll
        for (int j = 0; j < 4; ++j) acc[i][j] += ar_[i]*br_[j];
    }
  }
  const int colBase = nbase + tx*4;
  float bias[4];
  #pragma unroll
  for (int j = 0; j < 4; ++j) bias[j] = ba[m0*256 + colBase + j];
  #pragma unroll
  for (int i = 0; i < 4; ++i){
    int rowg = b*3136 + tile*64 + ty*4 + i;
    float4 o;
    o.x = acc[i][0] + bias[0];
    o.y = acc[i][1] + bias[1];
    o.z = acc[i][2] + bias[2];
    o.w = acc[i][3] + bias[3];
    *(float4*)(outp + (size_t)rowg*256 + colBase) = o;
  }
}

// ---------------------------------------------------------------------------
extern "C" void kernel_launch(void* const* d_in, const int* in_sizes, int n_in,
                              void* d_out, int out_size, void* d_ws, size_t ws_size,
                              hipStream_t stream)
{
  float* outp = (float*)d_out;
  const int FLAG_GRID = (out_size + 255)/256;

  if (n_in != 13) { flag_fill<<<FLAG_GRID,256,0,stream>>>(outp, out_size, 2000.f); return; }
  if (in_sizes[0] != 4*6*64*49*256) { flag_fill<<<FLAG_GRID,256,0,stream>>>(outp, out_size, 3000.f); return; }
  if (in_sizes[1] != 24) { flag_fill<<<FLAG_GRID,256,0,stream>>>(outp, out_size, 4000.f); return; }

  const size_t SZ_WFT  = (size_t)4*512*256*2;               //  1 MB (f16)
  const size_t SZ_BFF  = (size_t)4*512*sizeof(float);       //  8 KB
  const size_t SZ_Q    = (size_t)12544*256*2;               //  6.4 MB (f16)
  const size_t SZ_AOUT = (size_t)12544*256*2;               //  6.4 MB (f16)
  const size_t SZ_KW1  = (size_t)64*8*6*49*32*2;            //  9.63 MB / batch
  const size_t SZ_VM1  = (size_t)64*8*6*32*50*2;            //  9.83 MB / batch
  const size_t FIXED   = SZ_WFT + SZ_BFF + SZ_Q + SZ_AOUT;
  if (ws_size < FIXED + SZ_KW1 + SZ_VM1) { flag_fill<<<FLAG_GRID,256,0,stream>>>(outp, out_size, 1000.f); return; }

  int nb = 1;
  if (ws_size >= FIXED + 4*(SZ_KW1 + SZ_VM1)) nb = 4;
  else if (ws_size >= FIXED + 2*(SZ_KW1 + SZ_VM1)) nb = 2;

  const float* x    = (const float*)d_in[0];
  const int*   mode = (const int*)d_in[1];
  const float* Wq   = (const float*)d_in[2];
  const float* bq   = (const float*)d_in[3];
  const float* Wk   = (const float*)d_in[4];
  const float* bk   = (const float*)d_in[5];
  const float* Wv   = (const float*)d_in[6];
  const float* bv   = (const float*)d_in[7];
  const float* Wa   = (const float*)d_in[8];
  const float* ba   = (const float*)d_in[9];
  const float* Ratt = (const float*)d_in[10];
  const float* Rmsg = (const float*)d_in[11];
  const float* post = (const float*)d_in[12];

  char* w = (char*)d_ws;
  u16* Wft   = (u16*)w;   w += SZ_WFT;
  float* bff = (float*)w; w += SZ_BFF;
  u16* qbuf  = (u16*)w;   w += SZ_Q;
  u16* aout  = (u16*)w;   w += SZ_AOUT;
  u16* kwbuf = (u16*)w;   w += (size_t)nb*SZ_KW1;
  u16* vmbuf = (u16*)w;   w += (size_t)nb*SZ_VM1;

  fuse_w<<<dim3(4,256), 512, 0, stream>>>(Wk, Wv, Ratt, Rmsg, Wft);
  fuse_b<<<4, 512, 0, stream>>>(bk, bv, Ratt, Rmsg, bff);
  gemm_q<<<dim3(4,196), 256, 0, stream>>>(x, mode, Wq, bq, qbuf);
  for (int b0 = 0; b0 < 4; b0 += nb) {
    gemm_kwv<<<nb*588, 256, 0, stream>>>(x, mode, Wft, bff, kwbuf, vmbuf, b0);
    attn_kernel<<<nb*512, 64, 0, stream>>>(qbuf, kwbuf, vmbuf, post, aout, b0);
  }
  gemm_out<<<dim3(4,196), 256, 0, stream>>>(aout, mode, Wa, ba, outp);
}

// Round 8
// 402.659 us; speedup vs baseline: 1.2497x; 1.0377x over previous
//
#include <hip/hip_runtime.h>

typedef unsigned short u16;
typedef unsigned int   u32;
typedef _Float16 f16;
typedef _Float16 h2  __attribute__((ext_vector_type(2)));
typedef _Float16 h8  __attribute__((ext_vector_type(8)));
typedef float    fx4 __attribute__((ext_vector_type(4)));

// ---- problem constants ----
// B=4 L=6 X=Y=8 -> 256 sites, W=49 window, D=256, h=8, dh=32
#define SCALE_Q 0.17677669529663687f

__device__ __forceinline__ u16 f2h_bits(float f){
  union{ f16 h; u16 u; } v; v.h = (f16)f; return v.u;
}
__device__ __forceinline__ u32 packh2(float a, float b){
  union{ h2 h; u32 u; } v; v.h = h2{(f16)a, (f16)b}; return v.u;
}
__device__ __forceinline__ h2 as_h2(u32 x){
  union{ u32 u; h2 h; } v; v.u = x; return v.h;
}

// diagnostic fill (fp32): encodes which runtime assumption failed
__global__ void flag_fill(float* out, int n, float v){
  int i = blockIdx.x*256 + threadIdx.x;
  if (i < n) out[i] = v;
}

// ---------------------------------------------------------------------------
// K0: fuse relation matrices into projection weights (fp32 in, f16 out,
// TRANSPOSED for MFMA B-access): Wft[rel][n][d].
// ---------------------------------------------------------------------------
__global__ __launch_bounds__(512) void fuse_w(
    const float* __restrict__ Wk, const float* __restrict__ Wv,
    const float* __restrict__ Ratt, const float* __restrict__ Rmsg,
    u16* __restrict__ Wft)
{
  const int rel = blockIdx.x;      // 0..3
  const int d   = blockIdx.y;      // 0..255
  const int n   = threadIdx.x;     // 0..511
  const int ml  = rel & 1;
  float acc = 0.f;
  if (n < 256) {
    const int h = n >> 5, p = n & 31;
    const float* wcol = Wk + (size_t)ml*65536 + (size_t)(h*32)*256 + d;
    const float* rrow = Ratt + ((size_t)(rel*8 + h)*32 + p)*32;
    #pragma unroll
    for (int q = 0; q < 32; ++q) acc += wcol[q*256] * rrow[q];
  } else {
    const int n2 = n - 256, h = n2 >> 5, qq = n2 & 31;
    const float* wcol = Wv + (size_t)ml*65536 + (size_t)(h*32)*256 + d;
    const float* rcol = Rmsg + ((size_t)(rel*8 + h)*32)*32 + qq;
    #pragma unroll
    for (int p2 = 0; p2 < 32; ++p2) acc += wcol[p2*256] * rcol[p2*32];
  }
  Wft[((size_t)rel*512 + n)*256 + d] = f2h_bits(acc);
}

__global__ __launch_bounds__(512) void fuse_b(
    const float* __restrict__ bk, const float* __restrict__ bv,
    const float* __restrict__ Ratt, const float* __restrict__ Rmsg,
    float* __restrict__ bff)
{
  const int rel = blockIdx.x, n = threadIdx.x, ml = rel & 1;
  float acc = 0.f;
  if (n < 256) {
    const int h = n >> 5, p = n & 31;
    const float* rrow = Ratt + ((size_t)(rel*8 + h)*32 + p)*32;
    #pragma unroll
    for (int q = 0; q < 32; ++q) acc += bk[ml*256 + h*32 + q] * rrow[q];
  } else {
    const int n2 = n - 256, h = n2 >> 5, qq = n2 & 31;
    const float* rcol = Rmsg + ((size_t)(rel*8 + h)*32)*32 + qq;
    #pragma unroll
    for (int p2 = 0; p2 < 32; ++p2) acc += bv[ml*256 + h*32 + p2] * rcol[p2*32];
  }
  bff[rel*512 + n] = acc;
}

// ---------------------------------------------------------------------------
// K1 v4: fused kw / v_msg projection GEMM — MFMA (16x16x32 f16).
// BM=32, BN=512, grid = nb*588 (x fetched from HBM exactly once).
// A (32x256 fp32) staged to LDS f16 once (padded stride 264); barrier-free
// k-loop: 2 ds_read_b128 + 8 global b128 (B direct from L2-resident Wft) +
// 16 MFMA per wave per step. acc[2][8] = 64 VGPRs.
// EPILOGUE via LDS transpose (reuses the A buffer): each wave deposits its
// acc half into Smem[row][n] (bias applied), then all threads copy out with
// 4x b128 contiguous stores per half (thread = (row, h), 64 B each).
// Both outputs share ONE layout (f16):  kw/vm[bloc][xy][h][l][ef][p]
// ---------------------------------------------------------------------------
#define ASTRIDE 264   // u16 elements per LDS row (16B-aligned, conflict-light)

__global__ __launch_bounds__(256) void gemm_kwv(
    const float* __restrict__ x, const int* __restrict__ mode,
    const u16* __restrict__ Wft, const float* __restrict__ bff,
    u16* __restrict__ kw, u16* __restrict__ vm, int b0)
{
  __shared__ u16 Smem[32*ASTRIDE];   // 16.9 KB: A-tile, then epilogue buffer
  const int rowT  = blockIdx.x;              // bloc*588 + l*98 + tile
  const int bloc = rowT / 588;
  const int rem  = rowT % 588;
  const int l = rem / 98, tile = rem % 98;
  const int b = b0 + bloc;
  const int rel = mode[b*6]*2 + mode[b*6 + l];
  const float* Abase = x + ((size_t)(b*6 + l)*3136 + (size_t)tile*32)*256;
  const u16*   Bbase = Wft + (size_t)rel*131072;      // [n][d]
  const int tid  = threadIdx.x;
  const int wave = tid >> 6, lane = tid & 63;
  const int quad = lane >> 4, l15 = lane & 15;

  // ---- stage A once: thread t loads row t>>3, cols (t&7)*32..+31 ----
  {
    const int r = tid >> 3, cseg = (tid & 7)*32;
    const float* src = Abase + (size_t)r*256 + cseg;
    u16* dst = &Smem[r*ASTRIDE + cseg];
    #pragma unroll
    for (int i = 0; i < 4; ++i){
      float4 f0 = *(const float4*)(src + i*8);
      float4 f1 = *(const float4*)(src + i*8 + 4);
      uint4 pk;
      pk.x = packh2(f0.x, f0.y); pk.y = packh2(f0.z, f0.w);
      pk.z = packh2(f1.x, f1.y); pk.w = packh2(f1.z, f1.w);
      *(uint4*)(dst + i*8) = pk;
    }
  }
  __syncthreads();

  fx4 acc[2][8];
  #pragma unroll
  for (int mt = 0; mt < 2; ++mt)
    #pragma unroll
    for (int j = 0; j < 8; ++j) acc[mt][j] = fx4{0,0,0,0};

  // wave owns n-columns [wave*128, wave*128+128): 8 n-tiles x 2 m-tiles
  #pragma unroll
  for (int k0 = 0; k0 < 256; k0 += 32) {
    h8 af[2];
    #pragma unroll
    for (int mt = 0; mt < 2; ++mt)
      af[mt] = *(const h8*)&Smem[(mt*16 + l15)*ASTRIDE + k0 + quad*8];
    #pragma unroll
    for (int j = 0; j < 8; ++j){
      const int n = wave*128 + j*16 + l15;
      h8 bf = *(const h8*)(Bbase + (size_t)n*256 + k0 + quad*8);
      #pragma unroll
      for (int mt = 0; mt < 2; ++mt)
        acc[mt][j] = __builtin_amdgcn_mfma_f32_16x16x32_f16(af[mt], bf, acc[mt][j], 0, 0, 0);
    }
  }

  // ---- epilogue: LDS transpose, two halves (kw = waves 0,1 / vm = 2,3) ----
  const int row_ = tid >> 3;        // 0..31
  const int hsel = tid & 7;         // 0..7
  const int r_g  = tile*32 + row_;  // 0..3135
  const int xy   = r_g / 49, ef = r_g - xy*49;

  #pragma unroll
  for (int half = 0; half < 2; ++half){
    __syncthreads();   // protect Smem (A-tile reads / previous half's reads)
    if ((wave >> 1) == half){
      #pragma unroll
      for (int j = 0; j < 8; ++j){
        const int n   = wave*128 + j*16 + l15;
        const int col = n & 255;
        const float bias = bff[rel*512 + n];
        #pragma unroll
        for (int mt = 0; mt < 2; ++mt){
          #pragma unroll
          for (int reg = 0; reg < 4; ++reg){
            const int row = mt*16 + quad*4 + reg;
            Smem[row*ASTRIDE + col] = f2h_bits(acc[mt][j][reg] + bias);
          }
        }
      }
    }
    __syncthreads();
    u16* dbuf = half ? vm : kw;
    u16* dst  = dbuf + ((((size_t)(bloc*64 + xy)*8 + hsel)*6 + l)*49 + ef)*32;
    const u16* srcl = &Smem[row_*ASTRIDE + hsel*32];
    uint4 v0 = *(const uint4*)(srcl);
    uint4 v1 = *(const uint4*)(srcl + 8);
    uint4 v2 = *(const uint4*)(srcl + 16);
    uint4 v3 = *(const uint4*)(srcl + 24);
    *(uint4*)(dst)      = v0;
    *(uint4*)(dst + 8)  = v1;
    *(uint4*)(dst + 16) = v2;
    *(uint4*)(dst + 24) = v3;
  }
}

// ---------------------------------------------------------------------------
// K2: q projection (l=0 only), VALU 4x4, f16 output.
// ---------------------------------------------------------------------------
__global__ __launch_bounds__(256) void gemm_q(
    const float* __restrict__ x, const int* __restrict__ mode,
    const float* __restrict__ Wq, const float* __restrict__ bq,
    u16* __restrict__ qbuf)
{
  __shared__ float As[16][68];
  __shared__ float Bs[16][68];
  const int nbase = blockIdx.x * 64;      // 0..192
  const int rowT  = blockIdx.y;           // 0..195
  const int b = rowT / 49, tile = rowT % 49;
  const int m0 = mode[b*6];
  const float* Abase = x + ((size_t)b*6*3136 + (size_t)tile*64)*256;
  const float* Wbase = Wq + (size_t)m0*65536;
  const int tid = threadIdx.x;
  const int tx = tid & 15, ty = tid >> 4;
  const int arow = tid >> 2, acol = (tid & 3)*4;
  const int bn = tid >> 2,  bk4 = (tid & 3)*4;
  float acc[4][4] = {};
  for (int k0 = 0; k0 < 256; k0 += 16) {
    float4 ar = *(const float4*)(Abase + (size_t)arow*256 + k0 + acol);
    float4 br = *(const float4*)(Wbase + (size_t)(nbase + bn)*256 + k0 + bk4);
    __syncthreads();
    As[acol+0][arow]=ar.x; As[acol+1][arow]=ar.y; As[acol+2][arow]=ar.z; As[acol+3][arow]=ar.w;
    Bs[bk4+0][bn]=br.x; Bs[bk4+1][bn]=br.y; Bs[bk4+2][bn]=br.z; Bs[bk4+3][bn]=br.w;
    __syncthreads();
    #pragma unroll
    for (int kk = 0; kk < 16; ++kk){
      float4 a4 = *(const float4*)&As[kk][ty*4];
      float4 b4 = *(const float4*)&Bs[kk][tx*4];
      float ar_[4] = {a4.x,a4.y,a4.z,a4.w};
      float br_[4] = {b4.x,b4.y,b4.z,b4.w};
      #pragma unroll
      for (int i = 0; i < 4; ++i)
        #pragma unroll
        for (int j = 0; j < 4; ++j) acc[i][j] += ar_[i]*br_[j];
    }
  }
  const int colBase = nbase + tx*4;
  const int h = colBase >> 5, p = colBase & 31;
  float bias[4];
  #pragma unroll
  for (int j = 0; j < 4; ++j) bias[j] = bq[m0*256 + colBase + j];
  #pragma unroll
  for (int i = 0; i < 4; ++i){
    int r = tile*64 + ty*4 + i;
    int xy = r / 49, ef = r - xy*49;
    size_t dst = (((size_t)(b*64 + xy)*8 + h)*49 + ef)*32 + p;
    ushort4 pk;
    pk.x = f2h_bits((acc[i][0]+bias[0])*SCALE_Q);
    pk.y = f2h_bits((acc[i][1]+bias[1])*SCALE_Q);
    pk.z = f2h_bits((acc[i][2]+bias[2])*SCALE_Q);
    pk.w = f2h_bits((acc[i][3]+bias[3])*SCALE_Q);
    *(ushort4*)(qbuf + dst) = pk;
  }
}

// ---------------------------------------------------------------------------
// K3: attention — ONE WAVE per (bloc,xy,h); lane = query row qi (49 active).
// Scores S[49], online-softmax state, O[32] all in REGISTERS.
// K_z staged contiguously; V_z staged contiguously from the SAME [ef][p]
// layout and transposed into VT16[p][56] via u16 LDS writes (ef=49 pad
// zeroed once — uninitialized LDS could hold f16-Inf -> 0*Inf=NaN).
// QK^T and PV via v_dot2_f32_f16.
// ---------------------------------------------------------------------------
__global__ __launch_bounds__(64) void attn_kernel(
    const u16* __restrict__ qbuf, const u16* __restrict__ kw,
    const u16* __restrict__ vm,   const float* __restrict__ post,
    u16* __restrict__ aout, int b0)
{
  __shared__ float biasT[49*52];   // [ke][qi] — lane-linear reads
  __shared__ u32 Ks[784];          // K_z  flat [ef*16 + pp]
  __shared__ u16 VT16[32*56];      // V^T_z [p][56] (49 used, rest pad)
  __shared__ float poss[169];

  const int bloc  = blockIdx.x >> 9;
  const int local = blockIdx.x & 511;      // xy*8+h
  const int h = local & 7, xy = local >> 3;
  const int bxy = (b0 + bloc)*64 + xy;
  const int tid = threadIdx.x;             // 0..63
  const int qi = min(tid, 48);             // lane's query row (clamped)

  for (int i = tid; i < 169; i += 64) poss[i] = post[i*8 + h];
  if (tid < 32) VT16[tid*56 + 49] = 0;     // zero the ef=49 pad slot (once)
  __syncthreads();

  if (tid < 49){
    const int qa = qi/7, qb = qi - qa*7;
    for (int ka = 0; ka < 7; ++ka)
      for (int kb = 0; kb < 7; ++kb)
        biasT[(ka*7+kb)*52 + qi] = poss[(qa - ka + 6)*13 + (qb - kb + 6)];
  }

  // Q row into registers (16 u32 = 32 f16)
  u32 Qw[16];
  { const uint4* qsrc = (const uint4*)(qbuf + (size_t)(bxy*8 + h)*1568 + (size_t)qi*32);
    uint4 t0 = qsrc[0], t1 = qsrc[1], t2 = qsrc[2], t3 = qsrc[3];
    Qw[0]=t0.x; Qw[1]=t0.y; Qw[2]=t0.z; Qw[3]=t0.w;
    Qw[4]=t1.x; Qw[5]=t1.y; Qw[6]=t1.z; Qw[7]=t1.w;
    Qw[8]=t2.x; Qw[9]=t2.y; Qw[10]=t2.z; Qw[11]=t2.w;
    Qw[12]=t3.x; Qw[13]=t3.y; Qw[14]=t3.z; Qw[15]=t3.w; }

  const size_t kvbase = ((size_t)(bloc*64 + xy)*8 + h)*6;
  float mprev = -1e30f, lsum = 0.f;
  float O[32];
  #pragma unroll
  for (int p = 0; p < 32; ++p) O[p] = 0.f;

  for (int z = 0; z < 6; ++z){
    __syncthreads();   // prior phase's LDS reads complete (also covers biasT build)
    { const u32* ksrc = (const u32*)(kw) + (kvbase + z)*784;
      for (int i = tid; i < 784; i += 64) Ks[i] = ksrc[i];
      const u32* vsrc = (const u32*)(vm) + (kvbase + z)*784;
      for (int i = tid; i < 784; i += 64){
        u32 v2 = vsrc[i];
        int ef = i >> 4, pp = i & 15;
        VT16[(2*pp)*56 + ef]   = (u16)(v2 & 0xFFFFu);
        VT16[(2*pp+1)*56 + ef] = (u16)(v2 >> 16);
      } }
    __syncthreads();

    // ---- S[ke] = q . k_z + bias ----
    float S[49];
    #pragma unroll
    for (int ke = 0; ke < 49; ++ke){
      float s = biasT[ke*52 + qi];
      #pragma unroll
      for (int q4 = 0; q4 < 4; ++q4){
        uint4 k4 = *(const uint4*)&Ks[ke*16 + q4*4];
        s = __builtin_amdgcn_fdot2(as_h2(Qw[q4*4+0]), as_h2(k4.x), s, false);
        s = __builtin_amdgcn_fdot2(as_h2(Qw[q4*4+1]), as_h2(k4.y), s, false);
        s = __builtin_amdgcn_fdot2(as_h2(Qw[q4*4+2]), as_h2(k4.z), s, false);
        s = __builtin_amdgcn_fdot2(as_h2(Qw[q4*4+3]), as_h2(k4.w), s, false);
      }
      S[ke] = s;
    }

    // ---- online softmax (lane-local) ----
    float mx = mprev;
    #pragma unroll
    for (int ke = 0; ke < 49; ++ke) mx = fmaxf(mx, S[ke]);
    const float alpha = __expf(mprev - mx);
    float sum = 0.f;
    #pragma unroll
    for (int ke = 0; ke < 49; ++ke){ float e = __expf(S[ke]-mx); S[ke] = e; sum += e; }
    lsum = lsum*alpha + sum;
    mprev = mx;
    #pragma unroll
    for (int p = 0; p < 32; ++p) O[p] *= alpha;

    // ---- pack P to f16 pairs ----
    u32 Pp[25];
    #pragma unroll
    for (int kp = 0; kp < 24; ++kp) Pp[kp] = packh2(S[2*kp], S[2*kp+1]);
    Pp[24] = packh2(S[48], 0.f);

    // ---- O += P . V_z  (broadcast reads of VT16 as u32 pairs) ----
    const u32* VTs = (const u32*)VT16;   // index p*28 + rm
    #pragma unroll
    for (int p = 0; p < 32; ++p){
      float o = O[p];
      #pragma unroll
      for (int c = 0; c < 6; ++c){
        uint4 v4 = *(const uint4*)&VTs[p*28 + c*4];
        o = __builtin_amdgcn_fdot2(as_h2(Pp[c*4+0]), as_h2(v4.x), o, false);
        o = __builtin_amdgcn_fdot2(as_h2(Pp[c*4+1]), as_h2(v4.y), o, false);
        o = __builtin_amdgcn_fdot2(as_h2(Pp[c*4+2]), as_h2(v4.z), o, false);
        o = __builtin_amdgcn_fdot2(as_h2(Pp[c*4+3]), as_h2(v4.w), o, false);
      }
      o = __builtin_amdgcn_fdot2(as_h2(Pp[24]), as_h2(VTs[p*28 + 24]), o, false);
      O[p] = o;
    }
  }

  // ---- normalize + store (f16) ----
  if (tid < 49){
    const float inv = 1.f / lsum;
    u32* outw = (u32*)(aout + (size_t)bxy*12544 + h*32);
    #pragma unroll
    for (int pp = 0; pp < 16; ++pp)
      outw[(size_t)qi*128 + pp] = packh2(O[2*pp]*inv, O[2*pp+1]*inv);
  }
}

// ---------------------------------------------------------------------------
// K4: final projection. A = attn out (f16), B = Wa[m0] fp32 [e][d], bias ba.
// ---------------------------------------------------------------------------
__global__ __launch_bounds__(256) void gemm_out(
    const u16* __restrict__ aout, const int* __restrict__ mode,
    const float* __restrict__ Wa, const float* __restrict__ ba,
    float* __restrict__ outp)
{
  __shared__ float As[16][68];
  __shared__ float Bs[16][68];
  const int nbase = blockIdx.x * 64;
  const int rowT  = blockIdx.y;           // 0..195
  const int b = rowT / 49, tile = rowT % 49;
  const int m0 = mode[b*6];
  const u16* Abase = aout + ((size_t)b*3136 + (size_t)tile*64)*256;
  const float* Wbase = Wa + (size_t)m0*65536;
  const int tid = threadIdx.x;
  const int tx = tid & 15, ty = tid >> 4;
  const int arow = tid >> 2, acol = (tid & 3)*4;
  const int bn = tid >> 2,  bk4 = (tid & 3)*4;
  float acc[4][4] = {};
  for (int k0 = 0; k0 < 256; k0 += 16) {
    uint2  ar = *(const uint2*)(Abase + (size_t)arow*256 + k0 + acol);
    float4 br = *(const float4*)(Wbase + (size_t)(nbase + bn)*256 + k0 + bk4);
    __syncthreads();
    { h2 lo = as_h2(ar.x), hi = as_h2(ar.y);
      As[acol+0][arow]=(float)lo.x; As[acol+1][arow]=(float)lo.y;
      As[acol+2][arow]=(float)hi.x; As[acol+3][arow]=(float)hi.y; }
    Bs[bk4+0][bn]=br.x; Bs[bk4+1][bn]=br.y; Bs[bk4+2][bn]=br.z; Bs[bk4+3][bn]=br.w;
    __syncthreads();
    #pragma unroll
    for (int kk = 0; kk < 16; ++kk){
      float4 a4 = *(const float4*)&As[kk][ty*4];
      float4 b4 = *(const float4*)&Bs[kk][tx*4];
      float ar_[4] = {a4.x,a4.y,a4.z,a4.w};
      float br_[4] = {b4.x,b4.y,b4.z,b4.w};
      #pragma unroll
      for (int i = 0; i < 4; ++i)
        #pragma unroll
        for (int j = 0; j < 4; ++j) acc[i][j] += ar_[i]*br_[j];
    }
  }
  const int colBase = nbase + tx*4;
  float bias[4];
  #pragma unroll
  for (int j = 0; j < 4; ++j) bias[j] = ba[m0*256 + colBase + j];
  #pragma unroll
  for (int i = 0; i < 4; ++i){
    int rowg = b*3136 + tile*64 + ty*4 + i;
    float4 o;
    o.x = acc[i][0] + bias[0];
    o.y = acc[i][1] + bias[1];
    o.z = acc[i][2] + bias[2];
    o.w = acc[i][3] + bias[3];
    *(float4*)(outp + (size_t)rowg*256 + colBase) = o;
  }
}

// ---------------------------------------------------------------------------
extern "C" void kernel_launch(void* const* d_in, const int* in_sizes, int n_in,
                              void* d_out, int out_size, void* d_ws, size_t ws_size,
                              hipStream_t stream)
{
  float* outp = (float*)d_out;
  const int FLAG_GRID = (out_size + 255)/256;

  if (n_in != 13) { flag_fill<<<FLAG_GRID,256,0,stream>>>(outp, out_size, 2000.f); return; }
  if (in_sizes[0] != 4*6*64*49*256) { flag_fill<<<FLAG_GRID,256,0,stream>>>(outp, out_size, 3000.f); return; }
  if (in_sizes[1] != 24) { flag_fill<<<FLAG_GRID,256,0,stream>>>(outp, out_size, 4000.f); return; }

  const size_t SZ_WFT  = (size_t)4*512*256*2;               //  1 MB (f16)
  const size_t SZ_BFF  = (size_t)4*512*sizeof(float);       //  8 KB
  const size_t SZ_Q    = (size_t)12544*256*2;               //  6.4 MB (f16)
  const size_t SZ_AOUT = (size_t)12544*256*2;               //  6.4 MB (f16)
  const size_t SZ_KW1  = (size_t)64*8*6*49*32*2;            //  9.63 MB / batch
  const size_t SZ_VM1  = SZ_KW1;                            //  unified layout
  const size_t FIXED   = SZ_WFT + SZ_BFF + SZ_Q + SZ_AOUT;
  if (ws_size < FIXED + SZ_KW1 + SZ_VM1) { flag_fill<<<FLAG_GRID,256,0,stream>>>(outp, out_size, 1000.f); return; }

  int nb = 1;
  if (ws_size >= FIXED + 4*(SZ_KW1 + SZ_VM1)) nb = 4;
  else if (ws_size >= FIXED + 2*(SZ_KW1 + SZ_VM1)) nb = 2;

  const float* x    = (const float*)d_in[0];
  const int*   mode = (const int*)d_in[1];
  const float* Wq   = (const float*)d_in[2];
  const float* bq   = (const float*)d_in[3];
  const float* Wk   = (const float*)d_in[4];
  const float* bk   = (const float*)d_in[5];
  const float* Wv   = (const float*)d_in[6];
  const float* bv   = (const float*)d_in[7];
  const float* Wa   = (const float*)d_in[8];
  const float* ba   = (const float*)d_in[9];
  const float* Ratt = (const float*)d_in[10];
  const float* Rmsg = (const float*)d_in[11];
  const float* post = (const float*)d_in[12];

  char* w = (char*)d_ws;
  u16* Wft   = (u16*)w;   w += SZ_WFT;
  float* bff = (float*)w; w += SZ_BFF;
  u16* qbuf  = (u16*)w;   w += SZ_Q;
  u16* aout  = (u16*)w;   w += SZ_AOUT;
  u16* kwbuf = (u16*)w;   w += (size_t)nb*SZ_KW1;
  u16* vmbuf = (u16*)w;   w += (size_t)nb*SZ_VM1;

  fuse_w<<<dim3(4,256), 512, 0, stream>>>(Wk, Wv, Ratt, Rmsg, Wft);
  fuse_b<<<4, 512, 0, stream>>>(bk, bv, Ratt, Rmsg, bff);
  gemm_q<<<dim3(4,196), 256, 0, stream>>>(x, mode, Wq, bq, qbuf);
  for (int b0 = 0; b0 < 4; b0 += nb) {
    gemm_kwv<<<nb*588, 256, 0, stream>>>(x, mode, Wft, bff, kwbuf, vmbuf, b0);
    attn_kernel<<<nb*512, 64, 0, stream>>>(qbuf, kwbuf, vmbuf, post, aout, b0);
  }
  gemm_out<<<dim3(4,196), 256, 0, stream>>>(aout, mode, Wa, ba, outp);
}